// Round 9
// baseline (194.171 us; speedup 1.0000x reference)
//
#include <hip/hip_runtime.h>
#include <hip/hip_bf16.h>
#include <math.h>

#define NSEQ 2048
#define NB 4
#define NH 8
#define DH 64
#define DMODEL 512
#define MROWS (NSEQ * 4)

typedef short bf16x8 __attribute__((ext_vector_type(8)));
typedef float f32x4 __attribute__((ext_vector_type(4)));

static __device__ __forceinline__ short f2bf_r(float f) {
    unsigned u = __float_as_uint(f);
    u += 0x7FFF + ((u >> 16) & 1);
    return (short)(u >> 16);
}
static __device__ __forceinline__ unsigned bfpack(float a, float b) {
    unsigned ua = __float_as_uint(a); ua += 0x7FFF + ((ua >> 16) & 1);
    unsigned ub = __float_as_uint(b); ub += 0x7FFF + ((ub >> 16) & 1);
    return (ua >> 16) | (ub & 0xFFFF0000u);
}

// ---------------------------------------------------------------------------
// Kernel 0: one-shot prep.
//   xb[b*2048+n][d] <- bf16(x[n][b][d])
//   Wb rows: 0..511 Wq, 512..1023 Wk, 1024..1535 Wv, 1536..2047 Wo (bf16)
//   cs/sn[b][n][e] <- cos/sin(rope) (fp32 planes; rope reused 12x by k1)
// ---------------------------------------------------------------------------
__global__ __launch_bounds__(256) void k0_convert(
    const float* __restrict__ x, const float* __restrict__ Wq,
    const float* __restrict__ Wk, const float* __restrict__ Wv,
    const float* __restrict__ Wo, const float* __restrict__ rope,
    __hip_bfloat16* __restrict__ xb, __hip_bfloat16* __restrict__ Wb,
    float* __restrict__ cs, float* __restrict__ sn)
{
    const int idx = blockIdx.x * 256 + threadIdx.x;
    if (idx < 8192 * 128) {
        const int row = idx >> 7, c = (idx & 127) << 2;
        const int bi = row >> 11, ni = row & 2047;
        float4 v = *(const float4*)(x + ((size_t)(ni * NB + bi)) * DMODEL + c);
        uint2 u; u.x = bfpack(v.x, v.y); u.y = bfpack(v.z, v.w);
        *(uint2*)((short*)xb + (size_t)row * 512 + c) = u;
    } else if (idx < 8192 * 128 + 2048 * 128) {
        const int j = idx - 8192 * 128;
        const int row = j >> 7, c = (j & 127) << 2;
        const float* src = (row < 512) ? Wq : (row < 1024) ? Wk
                         : (row < 1536) ? Wv : Wo;
        const int rr = row & 511;
        float4 v = *(const float4*)(src + (size_t)rr * 512 + c);
        uint2 u; u.x = bfpack(v.x, v.y); u.y = bfpack(v.z, v.w);
        *(uint2*)((short*)Wb + (size_t)row * 512 + c) = u;
    } else {
        const int j = idx - (8192 * 128 + 2048 * 128);   // 0..131071
        float4 f = *(const float4*)(rope + (size_t)j * 4);
        float4 c4, s4;
        __sincosf(f.x, &s4.x, &c4.x);
        __sincosf(f.y, &s4.y, &c4.y);
        __sincosf(f.z, &s4.z, &c4.z);
        __sincosf(f.w, &s4.w, &c4.w);
        *(float4*)(cs + (size_t)j * 4) = c4;
        *(float4*)(sn + (size_t)j * 4) = s4;
    }
}

// ---------------------------------------------------------------------------
// Kernel 1a: Q/K projection with SWAPPED operands: C^T = W . x^T, so C rows
// are the e-dim -> each thread owns 4 CONSECUTIVE e (the r-quad). RoPE pairs
// are in-thread, cos/sin load as float4, and each (mi,ni) is one uint2 store
// into the k2 fragment-swizzled layout (wave stores 512B dense).
//   Q,K layout: [bh][tile16=n>>4][frag=e>>5][lane=((e>>3)&3)*16+(n&15)][j=e&7]
// ---------------------------------------------------------------------------
__global__ __launch_bounds__(256) void k1_qk(
    const __hip_bfloat16* __restrict__ xb, const float* __restrict__ cs,
    const float* __restrict__ sn, const __hip_bfloat16* __restrict__ Wb,
    __hip_bfloat16* __restrict__ Qs, __hip_bfloat16* __restrict__ Ks)
{
    __shared__ short As[128 * 72];   // x rows (n-dim)
    __shared__ short Bs[128 * 72];   // W rows (e-dim)
    const int t = threadIdx.x;
    const int w = t >> 6, L = t & 63, lo = L & 15, g = L >> 4;
    const int mhW = (w >> 1) << 6;   // e-half for this wave
    const int nhX = (w & 1) << 6;    // n-half

    const int lid = (int)(blockIdx.y * gridDim.x + blockIdx.x);
    const int xcd = lid & 7, slot = lid >> 3;
    const int row_blk = xcd * 8 + (slot & 7);     // 0..63  (x rows)
    const int col_blk = slot >> 3;                // 0..7   (W rows, Q|K)
    const int row0 = row_blk * 128, col0 = col_blk * 128;
    const int bi = row0 >> 11, ni0 = row0 & 2047;

    f32x4 acc[4][4] = {};                         // [e-tile][n-tile]
    for (int k0 = 0; k0 < DMODEL; k0 += 64) {
        __syncthreads();
#pragma unroll
        for (int c = 0; c < 4; ++c) {
            const int idx = c * 256 + t;
            const int m = idx >> 3, kb = idx & 7;
            *(uint4*)&As[m * 72 + kb * 8] =
                *(const uint4*)((const short*)xb + (size_t)(row0 + m) * 512 + k0 + kb * 8);
            *(uint4*)&Bs[m * 72 + kb * 8] =
                *(const uint4*)((const short*)Wb + (size_t)(col0 + m) * 512 + k0 + kb * 8);
        }
        __syncthreads();
#pragma unroll
        for (int ks = 0; ks < 2; ++ks) {
            bf16x8 af[4], bfr[4];
#pragma unroll
            for (int mi = 0; mi < 4; ++mi)   // A = W (e rows)
                af[mi] = *(const bf16x8*)&Bs[(mhW + mi * 16 + lo) * 72 + ks * 32 + g * 8];
#pragma unroll
            for (int ni = 0; ni < 4; ++ni)   // B = x (n cols)
                bfr[ni] = *(const bf16x8*)&As[(nhX + ni * 16 + lo) * 72 + ks * 32 + g * 8];
#pragma unroll
            for (int mi = 0; mi < 4; ++mi)
#pragma unroll
                for (int ni = 0; ni < 4; ++ni)
                    acc[mi][ni] = __builtin_amdgcn_mfma_f32_16x16x32_bf16(
                        af[mi], bfr[ni], acc[mi][ni], 0, 0, 0);
        }
    }

    const float SC = 0.125f * 1.44269504088896f;   // attn scale * log2(e) into Q
    short* outp = (short*)((col0 < 512) ? Qs : Ks);
    const float qs = (col0 < 512) ? SC : 1.0f;
    const int cbase = col0 & 511;
#pragma unroll
    for (int mi = 0; mi < 4; ++mi) {
        const int c0 = cbase + mhW + mi * 16 + (g << 2);   // 4 consecutive e
        const int h = c0 >> 6, e0 = c0 & 63;
        short* hb = outp + ((size_t)(bi * NH + h)) * 131072
                    + (e0 >> 5) * 512 + ((e0 >> 3) & 3) * 128 + (e0 & 7);
#pragma unroll
        for (int ni = 0; ni < 4; ++ni) {
            const int nseq = ni0 + nhX + ni * 16 + lo;
            const float4 c4 = *(const float4*)(cs + ((size_t)bi * NSEQ + nseq) * DH + e0);
            const float4 s4 = *(const float4*)(sn + ((size_t)bi * NSEQ + nseq) * DH + e0);
            const f32x4 v = acc[mi][ni];
            const float o0 = (v[0] * c4.x - v[1] * s4.x) * qs;
            const float o1 = (v[1] * c4.y + v[0] * s4.y) * qs;
            const float o2 = (v[2] * c4.z - v[3] * s4.z) * qs;
            const float o3 = (v[3] * c4.w + v[2] * s4.w) * qs;
            uint2 u; u.x = bfpack(o0, o1); u.y = bfpack(o2, o3);
            *(uint2*)(hb + (size_t)(nseq >> 4) * 1024 + (nseq & 15) * 8) = u;
        }
    }
}

// ---------------------------------------------------------------------------
// Kernel 1b: V projection (original orientation: C rows = n). Epilogue packs
// 4 consecutive n as uint2 into the V^T fragment-swizzled layout:
//   V^T: [bh][k32=n>>5][d16=e>>4][lane=((n>>3)&3)*16+(e&15)][j=n&7]
// ---------------------------------------------------------------------------
__global__ __launch_bounds__(256) void k1_v(
    const __hip_bfloat16* __restrict__ xb, const __hip_bfloat16* __restrict__ Wb,
    __hip_bfloat16* __restrict__ Vs)
{
    __shared__ short As[128 * 72];
    __shared__ short Bs[128 * 72];
    const int t = threadIdx.x;
    const int w = t >> 6, L = t & 63, lo = L & 15, g = L >> 4;
    const int mh = (w >> 1) << 6, nh = (w & 1) << 6;

    const int lid = (int)(blockIdx.y * gridDim.x + blockIdx.x);
    const int xcd = lid & 7, slot = lid >> 3;
    const int row_blk = xcd * 8 + (slot & 7);     // 0..63
    const int col_blk = slot >> 3;                // 0..3
    const int row0 = row_blk * 128, col0 = col_blk * 128;
    const int bi = row0 >> 11, ni0 = row0 & 2047;

    f32x4 acc[4][4] = {};
    for (int k0 = 0; k0 < DMODEL; k0 += 64) {
        __syncthreads();
#pragma unroll
        for (int c = 0; c < 4; ++c) {
            const int idx = c * 256 + t;
            const int m = idx >> 3, kb = idx & 7;
            *(uint4*)&As[m * 72 + kb * 8] =
                *(const uint4*)((const short*)xb + (size_t)(row0 + m) * 512 + k0 + kb * 8);
            *(uint4*)&Bs[m * 72 + kb * 8] =
                *(const uint4*)((const short*)Wb + (size_t)(1024 + col0 + m) * 512 + k0 + kb * 8);
        }
        __syncthreads();
#pragma unroll
        for (int ks = 0; ks < 2; ++ks) {
            bf16x8 af[4], bfr[4];
#pragma unroll
            for (int mi = 0; mi < 4; ++mi)
                af[mi] = *(const bf16x8*)&As[(mh + mi * 16 + lo) * 72 + ks * 32 + g * 8];
#pragma unroll
            for (int ni = 0; ni < 4; ++ni)
                bfr[ni] = *(const bf16x8*)&Bs[(nh + ni * 16 + lo) * 72 + ks * 32 + g * 8];
#pragma unroll
            for (int mi = 0; mi < 4; ++mi)
#pragma unroll
                for (int ni = 0; ni < 4; ++ni)
                    acc[mi][ni] = __builtin_amdgcn_mfma_f32_16x16x32_bf16(
                        af[mi], bfr[ni], acc[mi][ni], 0, 0, 0);
        }
    }
#pragma unroll
    for (int ni = 0; ni < 4; ++ni) {
        const int c = col0 + nh + ni * 16 + lo;   // 0..511
        const int h = c >> 6, e = c & 63;
        short* hb = (short*)Vs + ((size_t)(bi * NH + h)) * 131072
                    + (e >> 4) * 512 + (e & 15) * 8;
#pragma unroll
        for (int mi = 0; mi < 4; ++mi) {
            const int nb = ni0 + mh + mi * 16 + g * 4;   // 4 consecutive n
            uint2 u;
            u.x = bfpack(acc[mi][ni][0], acc[mi][ni][1]);
            u.y = bfpack(acc[mi][ni][2], acc[mi][ni][3]);
            *(uint2*)(hb + (size_t)(nb >> 5) * 2048 + ((nb >> 3) & 3) * 128
                      + (nb & 7)) = u;
        }
    }
}

// ---------------------------------------------------------------------------
// Kernel 2: causal flash attention — barrier-free, register-pipelined (R8).
// ---------------------------------------------------------------------------
__global__ __launch_bounds__(256, 3) void k2_attn(
    const __hip_bfloat16* __restrict__ Qs, const __hip_bfloat16* __restrict__ Ks,
    const __hip_bfloat16* __restrict__ Vs, const float* __restrict__ head_scale,
    __hip_bfloat16* __restrict__ Ob)
{
    __shared__ short sP[4][16 * 72];   // per-wave P buffer [q][key]

    const int t = threadIdx.x;
    const int w = t >> 6, L = t & 63, lo = L & 15, g = L >> 4;

    const int lid = (int)blockIdx.x;
    const int xcd = lid & 7, slot = lid >> 3;        // 0..127 per XCD
    const int bh = xcd * 4 + (slot & 3);             // 4 heads per XCD
    const int qb = 31 - (slot >> 2);                 // heavy blocks first
    const int qt = qb * 4 + w;
    const int bi = bh >> 3, h = bh & 7;

    const short* Kp = (const short*)Ks + (size_t)bh * (128 * 1024) + L * 8;
    const short* Vp = (const short*)Vs + (size_t)bh * (256 * 512) + L * 8;
    const short* Qp = (const short*)Qs + (size_t)bh * (128 * 1024)
                      + (size_t)qt * 1024 + L * 8;
    const bf16x8 qf0 = *(const bf16x8*)(Qp);
    const bf16x8 qf1 = *(const bf16x8*)(Qp + 512);

    f32x4 acc[4] = {};
    float l_i = 0.f;
    const int nkt = qb + 1;

    auto body = [&](const bf16x8* kc0, const bf16x8* kc1, int kt) {
        const bool diag = (kt == qb);
        const int mlim = diag ? w : 3;
        const bool hi = (mlim >= 2);

        bf16x8 vb0[4], vb1[4];
        const short* vp0 = Vp + (size_t)(kt * 8) * 512;
#pragma unroll
        for (int dt = 0; dt < 4; ++dt) {
            vb0[dt] = *(const bf16x8*)(vp0 + dt * 512);
            if (hi) vb1[dt] = *(const bf16x8*)(vp0 + (4 + dt) * 512);
        }

        f32x4 s[4];
#pragma unroll
        for (int mt = 0; mt < 4; ++mt) {
            if (mt <= mlim) {
                f32x4 z = {};
                z = __builtin_amdgcn_mfma_f32_16x16x32_bf16(kc0[mt], qf0, z, 0, 0, 0);
                s[mt] = __builtin_amdgcn_mfma_f32_16x16x32_bf16(kc1[mt], qf1, z, 0, 0, 0);
                if (diag && mt == mlim) {
#pragma unroll
                    for (int r = 0; r < 4; ++r)
                        if ((g * 4 + r) > lo) s[mt][r] = -1e30f;
                }
            }
        }

#pragma unroll
        for (int mt = 0; mt < 4; ++mt) {
            uint2 u;
            if (mt <= mlim) {
                const float p0 = exp2f(s[mt][0] - 16.f);
                const float p1 = exp2f(s[mt][1] - 16.f);
                const float p2 = exp2f(s[mt][2] - 16.f);
                const float p3 = exp2f(s[mt][3] - 16.f);
                l_i += (p0 + p1) + (p2 + p3);
                u.x = bfpack(p0, p1); u.y = bfpack(p2, p3);
            } else {
                u.x = 0u; u.y = 0u;
            }
            *(uint2*)&sP[w][lo * 72 + mt * 16 + g * 4] = u;
        }

        const bf16x8 pb0 = *(const bf16x8*)&sP[w][lo * 72 + g * 8];
        if (hi) {
            const bf16x8 pb1 = *(const bf16x8*)&sP[w][lo * 72 + 32 + g * 8];
#pragma unroll
            for (int dt = 0; dt < 4; ++dt) {
                acc[dt] = __builtin_amdgcn_mfma_f32_16x16x32_bf16(vb0[dt], pb0, acc[dt], 0, 0, 0);
                acc[dt] = __builtin_amdgcn_mfma_f32_16x16x32_bf16(vb1[dt], pb1, acc[dt], 0, 0, 0);
            }
        } else {
#pragma unroll
            for (int dt = 0; dt < 4; ++dt)
                acc[dt] = __builtin_amdgcn_mfma_f32_16x16x32_bf16(vb0[dt], pb0, acc[dt], 0, 0, 0);
        }
    };

    bf16x8 kA0[4], kA1[4], kB0[4], kB1[4];
#pragma unroll
    for (int mt = 0; mt < 4; ++mt) {
        const short* kp = Kp + (size_t)mt * 1024;
        kA0[mt] = *(const bf16x8*)kp;
        kA1[mt] = *(const bf16x8*)(kp + 512);
    }
    int kt = 0;
#pragma unroll 1
    while (true) {
        if (kt + 1 < nkt) {
            const short* kp = Kp + (size_t)((kt + 1) * 4) * 1024;
#pragma unroll
            for (int mt = 0; mt < 4; ++mt) {
                kB0[mt] = *(const bf16x8*)(kp + mt * 1024);
                kB1[mt] = *(const bf16x8*)(kp + mt * 1024 + 512);
            }
        }
        body(kA0, kA1, kt);
        ++kt;
        if (kt >= nkt) break;
        if (kt + 1 < nkt) {
            const short* kp = Kp + (size_t)((kt + 1) * 4) * 1024;
#pragma unroll
            for (int mt = 0; mt < 4; ++mt) {
                kA0[mt] = *(const bf16x8*)(kp + mt * 1024);
                kA1[mt] = *(const bf16x8*)(kp + mt * 1024 + 512);
            }
        }
        body(kB0, kB1, kt);
        ++kt;
        if (kt >= nkt) break;
    }

    l_i += __shfl_xor(l_i, 16);
    l_i += __shfl_xor(l_i, 32);
    const float f = head_scale[h] / l_i;
    const int q = qt * 16 + lo;
    short* op = (short*)Ob + ((size_t)bi * NSEQ + q) * DMODEL + h * DH + g * 4;
#pragma unroll
    for (int dt = 0; dt < 4; ++dt) {
        uint2 u;
        u.x = bfpack(acc[dt][0] * f, acc[dt][1] * f);
        u.y = bfpack(acc[dt][2] * f, acc[dt][3] * f);
        *(uint2*)(op + dt * 16) = u;
    }
}

// ---------------------------------------------------------------------------
// Kernel 3: out projection, pure-bf16 MFMA (XCD remap).
// ---------------------------------------------------------------------------
__global__ __launch_bounds__(256) void k3_proj(
    const __hip_bfloat16* __restrict__ Ob, const __hip_bfloat16* __restrict__ Wob,
    const float* __restrict__ bo, float* __restrict__ C2)
{
    __shared__ short As[128 * 72];
    __shared__ short Bs[128 * 72];
    const int t = threadIdx.x;
    const int w = t >> 6, L = t & 63, lo = L & 15, g = L >> 4;
    const int mh = (w >> 1) << 6, nh = (w & 1) << 6;

    const int lid = (int)(blockIdx.y * gridDim.x + blockIdx.x);
    const int xcd = lid & 7, slot = lid >> 3;
    const int row_blk = xcd * 8 + (slot & 7);
    const int col_blk = slot >> 3;
    const int row0 = row_blk * 128, col0 = col_blk * 128;

    f32x4 acc[4][4] = {};
    for (int k0 = 0; k0 < DMODEL; k0 += 64) {
        __syncthreads();
#pragma unroll
        for (int c = 0; c < 4; ++c) {
            const int idx = c * 256 + t;
            const int m = idx >> 3, kb = idx & 7;
            *(uint4*)&As[m * 72 + kb * 8] =
                *(const uint4*)((const short*)Ob + (size_t)(row0 + m) * 512 + k0 + kb * 8);
            *(uint4*)&Bs[m * 72 + kb * 8] =
                *(const uint4*)((const short*)Wob + (size_t)(col0 + m) * 512 + k0 + kb * 8);
        }
        __syncthreads();
#pragma unroll
        for (int ks = 0; ks < 2; ++ks) {
            bf16x8 af[4], bfr[4];
#pragma unroll
            for (int mi = 0; mi < 4; ++mi)
                af[mi] = *(const bf16x8*)&As[(mh + mi * 16 + lo) * 72 + ks * 32 + g * 8];
#pragma unroll
            for (int ni = 0; ni < 4; ++ni)
                bfr[ni] = *(const bf16x8*)&Bs[(nh + ni * 16 + lo) * 72 + ks * 32 + g * 8];
#pragma unroll
            for (int mi = 0; mi < 4; ++mi)
#pragma unroll
                for (int ni = 0; ni < 4; ++ni)
                    acc[mi][ni] = __builtin_amdgcn_mfma_f32_16x16x32_bf16(
                        af[mi], bfr[ni], acc[mi][ni], 0, 0, 0);
        }
    }
#pragma unroll
    for (int ni = 0; ni < 4; ++ni) {
        const int c = col0 + nh + ni * 16 + lo;
        const float b = bo[c];
#pragma unroll
        for (int mi = 0; mi < 4; ++mi) {
#pragma unroll
            for (int r = 0; r < 4; ++r) {
                const int m = row0 + mh + mi * 16 + g * 4 + r;
                C2[(size_t)m * DMODEL + c] = acc[mi][ni][r] + b;
            }
        }
    }
}

// ---------------------------------------------------------------------------
// Kernel 4: LayerNorm + ls_scale + transpose store to (n,b,d)
// ---------------------------------------------------------------------------
__global__ __launch_bounds__(256) void k4_ln(
    const float* __restrict__ C2, const float* __restrict__ g,
    const float* __restrict__ bln, const float* __restrict__ ls,
    float* __restrict__ out)
{
    const int m = blockIdx.x;
    const int bi = m >> 11, ni = m & (NSEQ - 1);
    const float* row = C2 + (size_t)m * DMODEL;
    const int t = threadIdx.x;
    float v0 = row[t], v1 = row[t + 256];
    float s = v0 + v1, sq2 = v0 * v0 + v1 * v1;
#pragma unroll
    for (int off = 32; off > 0; off >>= 1) {
        s += __shfl_down(s, off);
        sq2 += __shfl_down(sq2, off);
    }
    __shared__ float red[8];
    const int wid = t >> 6;
    if ((t & 63) == 0) { red[wid] = s; red[wid + 4] = sq2; }
    __syncthreads();
    s = red[0] + red[1] + red[2] + red[3];
    sq2 = red[4] + red[5] + red[6] + red[7];
    const float mean = s * (1.f / 512.f);
    const float var = sq2 * (1.f / 512.f) - mean * mean;
    const float rstd = rsqrtf(var + 1e-5f);
    float* ob = out + ((size_t)ni * NB + bi) * DMODEL;
    ob[t]       = ((v0 - mean) * rstd * g[t]       + bln[t])       * ls[t];
    ob[t + 256] = ((v1 - mean) * rstd * g[t + 256] + bln[t + 256]) * ls[t + 256];
}

// ---------------------------------------------------------------------------
extern "C" void kernel_launch(void* const* d_in, const int* in_sizes, int n_in,
                              void* d_out, int out_size, void* d_ws, size_t ws_size,
                              hipStream_t stream) {
    const float* x          = (const float*)d_in[0];
    const float* rope       = (const float*)d_in[1];
    const float* Wq         = (const float*)d_in[2];
    const float* Wk         = (const float*)d_in[3];
    const float* Wv         = (const float*)d_in[4];
    const float* Wo         = (const float*)d_in[5];
    const float* bo         = (const float*)d_in[6];
    const float* ln_g       = (const float*)d_in[7];
    const float* ln_b       = (const float*)d_in[8];
    const float* head_scale = (const float*)d_in[9];
    const float* ls_scale   = (const float*)d_in[10];
    float* out = (float*)d_out;

    char* wsb = (char*)d_ws;
    __hip_bfloat16* xb  = (__hip_bfloat16*)(wsb);                       // 8 MB
    __hip_bfloat16* Wb  = (__hip_bfloat16*)(wsb + ((size_t) 8 << 20));  // 2 MB
    __hip_bfloat16* Qs  = (__hip_bfloat16*)(wsb + ((size_t)10 << 20));  // 8 MB
    __hip_bfloat16* Ks  = (__hip_bfloat16*)(wsb + ((size_t)18 << 20));  // 8 MB
    __hip_bfloat16* Vs  = (__hip_bfloat16*)(wsb + ((size_t)26 << 20));  // 8 MB
    __hip_bfloat16* Ob  = (__hip_bfloat16*)(wsb + ((size_t)34 << 20));  // 8 MB
    float*          cs  = (float*)(wsb + ((size_t)42 << 20));           // 2 MB
    float*          sn  = (float*)(wsb + ((size_t)44 << 20));           // 2 MB
    float*          C2  = (float*)(wsb + ((size_t)10 << 20));           // 16 MB, overlaps Q/K
    __hip_bfloat16* Wob = Wb + (size_t)1536 * 512;

    k0_convert<<<5632, 256, 0, stream>>>(x, Wq, Wk, Wv, Wo, rope, xb, Wb, cs, sn);
    k1_qk<<<dim3(64, 8), 256, 0, stream>>>(xb, cs, sn, Wb, Qs, Ks);
    k1_v<<<dim3(64, 4), 256, 0, stream>>>(xb, Wb, Vs);
    k2_attn<<<1024, 256, 0, stream>>>(Qs, Ks, Vs, head_scale, Ob);
    k3_proj<<<dim3(64, 4), 256, 0, stream>>>(Ob, Wob, bo, C2);
    k4_ln<<<MROWS, 256, 0, stream>>>(C2, ln_g, ln_b, ls_scale, out);
}

// Round 10
// 184.844 us; speedup vs baseline: 1.0505x; 1.0505x over previous
//
#include <hip/hip_runtime.h>
#include <hip/hip_bf16.h>
#include <math.h>

#define NSEQ 2048
#define NB 4
#define NH 8
#define DH 64
#define DMODEL 512
#define MROWS (NSEQ * 4)

typedef short bf16x8 __attribute__((ext_vector_type(8)));
typedef float f32x4 __attribute__((ext_vector_type(4)));

static __device__ __forceinline__ short f2bf_r(float f) {
    unsigned u = __float_as_uint(f);
    u += 0x7FFF + ((u >> 16) & 1);
    return (short)(u >> 16);
}
static __device__ __forceinline__ unsigned bfpack(float a, float b) {   // RNE
    unsigned ua = __float_as_uint(a); ua += 0x7FFF + ((ua >> 16) & 1);
    unsigned ub = __float_as_uint(b); ub += 0x7FFF + ((ub >> 16) & 1);
    return (ua >> 16) | (ub & 0xFFFF0000u);
}
static __device__ __forceinline__ unsigned bfpack_f(float a, float b) { // fast, p>=0
    unsigned ua = (__float_as_uint(a) + 0x8000u) >> 16;
    unsigned ub = (__float_as_uint(b) + 0x8000u) & 0xFFFF0000u;
    return ua | ub;
}
static __device__ __forceinline__ float bf2f(unsigned short u) {
    return __uint_as_float(((unsigned)u) << 16);
}

// ---------------------------------------------------------------------------
// Kernel 0: one-shot prep: xb bf16 (b,n,d); Wb bf16 cat(Wq,Wk,Wv,Wo);
// cs/sn fp32 cos/sin planes of rope.
// ---------------------------------------------------------------------------
__global__ __launch_bounds__(256) void k0_convert(
    const float* __restrict__ x, const float* __restrict__ Wq,
    const float* __restrict__ Wk, const float* __restrict__ Wv,
    const float* __restrict__ Wo, const float* __restrict__ rope,
    __hip_bfloat16* __restrict__ xb, __hip_bfloat16* __restrict__ Wb,
    float* __restrict__ cs, float* __restrict__ sn)
{
    const int idx = blockIdx.x * 256 + threadIdx.x;
    if (idx < 8192 * 128) {
        const int row = idx >> 7, c = (idx & 127) << 2;
        const int bi = row >> 11, ni = row & 2047;
        float4 v = *(const float4*)(x + ((size_t)(ni * NB + bi)) * DMODEL + c);
        uint2 u; u.x = bfpack(v.x, v.y); u.y = bfpack(v.z, v.w);
        *(uint2*)((short*)xb + (size_t)row * 512 + c) = u;
    } else if (idx < 8192 * 128 + 2048 * 128) {
        const int j = idx - 8192 * 128;
        const int row = j >> 7, c = (j & 127) << 2;
        const float* src = (row < 512) ? Wq : (row < 1024) ? Wk
                         : (row < 1536) ? Wv : Wo;
        const int rr = row & 511;
        float4 v = *(const float4*)(src + (size_t)rr * 512 + c);
        uint2 u; u.x = bfpack(v.x, v.y); u.y = bfpack(v.z, v.w);
        *(uint2*)((short*)Wb + (size_t)row * 512 + c) = u;
    } else {
        const int j = idx - (8192 * 128 + 2048 * 128);   // 0..131071
        float4 f = *(const float4*)(rope + (size_t)j * 4);
        float4 c4, s4;
        __sincosf(f.x, &s4.x, &c4.x);
        __sincosf(f.y, &s4.y, &c4.y);
        __sincosf(f.z, &s4.z, &c4.z);
        __sincosf(f.w, &s4.w, &c4.w);
        *(float4*)(cs + (size_t)j * 4) = c4;
        *(float4*)(sn + (size_t)j * 4) = s4;
    }
}

// ---------------------------------------------------------------------------
// Kernel 1: merged QKV projection (one kernel, region-branched orientation).
// Q/K blocks (col_blk<8): swapped operands C^T = W.x^T -> thread owns 4
// consecutive e; in-thread RoPE; dense uint2 stores to swizzled layout.
// V blocks (col_blk>=8): normal orientation; dense uint2 stores to V^T
// swizzled layout. Staging is identical for all regions (Wb rows col_blk*128).
//   Q,K: [bh][n>>4][e>>5][((e>>3)&3)*16+(n&15)][e&7]
//   V^T: [bh][n>>5][e>>4][((n>>3)&3)*16+(e&15)][n&7]
// ---------------------------------------------------------------------------
__global__ __launch_bounds__(256) void k1_qkv(
    const __hip_bfloat16* __restrict__ xb, const float* __restrict__ cs,
    const float* __restrict__ sn, const __hip_bfloat16* __restrict__ Wb,
    __hip_bfloat16* __restrict__ Qs, __hip_bfloat16* __restrict__ Ks,
    __hip_bfloat16* __restrict__ Vs)
{
    __shared__ short As[128 * 72];   // x rows (n-dim)
    __shared__ short Bs[128 * 72];   // W rows (e-dim)
    const int t = threadIdx.x;
    const int w = t >> 6, L = t & 63, lo = L & 15, g = L >> 4;
    const int ah = (w >> 1) << 6;    // A-matrix half (rows of A)
    const int bhh = (w & 1) << 6;    // B-matrix half

    const int lid = (int)(blockIdx.y * gridDim.x + blockIdx.x);
    const int xcd = lid & 7, slot = lid >> 3;
    const int row_blk = xcd * 8 + (slot & 7);     // 0..63  (x rows)
    const int col_blk = slot >> 3;                // 0..11  (Wb rows /128)
    const int row0 = row_blk * 128, wrow0 = col_blk * 128;
    const int bi = row0 >> 11, ni0 = row0 & 2047;
    const bool isV = (col_blk >= 8);

    f32x4 acc[4][4] = {};
    for (int k0 = 0; k0 < DMODEL; k0 += 64) {
        __syncthreads();
#pragma unroll
        for (int c = 0; c < 4; ++c) {
            const int idx = c * 256 + t;
            const int m = idx >> 3, kb = idx & 7;
            *(uint4*)&As[m * 72 + kb * 8] =
                *(const uint4*)((const short*)xb + (size_t)(row0 + m) * 512 + k0 + kb * 8);
            *(uint4*)&Bs[m * 72 + kb * 8] =
                *(const uint4*)((const short*)Wb + (size_t)(wrow0 + m) * 512 + k0 + kb * 8);
        }
        __syncthreads();
        const short* Abuf = isV ? As : Bs;   // A rows: x(n) for V, W(e) for Q/K
        const short* Bbuf = isV ? Bs : As;
#pragma unroll
        for (int ks = 0; ks < 2; ++ks) {
            bf16x8 af[4], bfr[4];
#pragma unroll
            for (int mi = 0; mi < 4; ++mi)
                af[mi] = *(const bf16x8*)&Abuf[(ah + mi * 16 + lo) * 72 + ks * 32 + g * 8];
#pragma unroll
            for (int ni = 0; ni < 4; ++ni)
                bfr[ni] = *(const bf16x8*)&Bbuf[(bhh + ni * 16 + lo) * 72 + ks * 32 + g * 8];
#pragma unroll
            for (int mi = 0; mi < 4; ++mi)
#pragma unroll
                for (int ni = 0; ni < 4; ++ni)
                    acc[mi][ni] = __builtin_amdgcn_mfma_f32_16x16x32_bf16(
                        af[mi], bfr[ni], acc[mi][ni], 0, 0, 0);
        }
    }

    if (!isV) {
        // --- Q/K epilogue: rows of C = e-dim (4 consecutive e per thread) ---
        const float SC = 0.125f * 1.44269504088896f;
        short* outp = (short*)((wrow0 < 512) ? Qs : Ks);
        const float qs = (wrow0 < 512) ? SC : 1.0f;
        const int cbase = wrow0 & 511;
#pragma unroll
        for (int mi = 0; mi < 4; ++mi) {
            const int c0 = cbase + ah + mi * 16 + (g << 2);   // 4 consecutive e
            const int h = c0 >> 6, e0 = c0 & 63;
            short* hb = outp + ((size_t)(bi * NH + h)) * 131072
                        + (e0 >> 5) * 512 + ((e0 >> 3) & 3) * 128 + (e0 & 7);
#pragma unroll
            for (int ni = 0; ni < 4; ++ni) {
                const int nseq = ni0 + bhh + ni * 16 + lo;
                const float4 c4 = *(const float4*)(cs + ((size_t)bi * NSEQ + nseq) * DH + e0);
                const float4 s4 = *(const float4*)(sn + ((size_t)bi * NSEQ + nseq) * DH + e0);
                const f32x4 v = acc[mi][ni];
                const float o0 = (v[0] * c4.x - v[1] * s4.x) * qs;
                const float o1 = (v[1] * c4.y + v[0] * s4.y) * qs;
                const float o2 = (v[2] * c4.z - v[3] * s4.z) * qs;
                const float o3 = (v[3] * c4.w + v[2] * s4.w) * qs;
                uint2 u; u.x = bfpack(o0, o1); u.y = bfpack(o2, o3);
                *(uint2*)(hb + (size_t)(nseq >> 4) * 1024 + (nseq & 15) * 8) = u;
            }
        }
    } else {
        // --- V epilogue: rows of C = n-dim (4 consecutive n per thread) ---
        const int col0 = wrow0 - 1024;   // 0..383 step 128
#pragma unroll
        for (int ni = 0; ni < 4; ++ni) {
            const int c = col0 + bhh + ni * 16 + lo;   // 0..511
            const int h = c >> 6, e = c & 63;
            short* hb = (short*)Vs + ((size_t)(bi * NH + h)) * 131072
                        + (e >> 4) * 512 + (e & 15) * 8;
#pragma unroll
            for (int mi = 0; mi < 4; ++mi) {
                const int nb = ni0 + ah + mi * 16 + g * 4;   // 4 consecutive n
                uint2 u;
                u.x = bfpack(acc[mi][ni][0], acc[mi][ni][1]);
                u.y = bfpack(acc[mi][ni][2], acc[mi][ni][3]);
                *(uint2*)(hb + (size_t)(nb >> 5) * 2048 + ((nb >> 3) & 3) * 128
                          + (nb & 7)) = u;
            }
        }
    }
}

// ---------------------------------------------------------------------------
// Kernel 2: causal flash attention — barrier-free, register-pipelined,
// VALU-slimmed: raw exp2f(s) (the fixed bias cancels exactly in O/l),
// fast bf16 pack for P, hoisted pointer arithmetic.
// ---------------------------------------------------------------------------
__global__ __launch_bounds__(256, 3) void k2_attn(
    const __hip_bfloat16* __restrict__ Qs, const __hip_bfloat16* __restrict__ Ks,
    const __hip_bfloat16* __restrict__ Vs, const float* __restrict__ head_scale,
    __hip_bfloat16* __restrict__ Ob)
{
    __shared__ short sP[4][16 * 72];   // per-wave P buffer [q][key]

    const int t = threadIdx.x;
    const int w = t >> 6, L = t & 63, lo = L & 15, g = L >> 4;

    const int lid = (int)blockIdx.x;
    const int xcd = lid & 7, slot = lid >> 3;        // 0..127 per XCD
    const int bh = xcd * 4 + (slot & 3);             // 4 heads per XCD
    const int qb = 31 - (slot >> 2);                 // heavy blocks first
    const int qt = qb * 4 + w;
    const int bi = bh >> 3, h = bh & 7;

    const short* Kp = (const short*)Ks + (size_t)bh * 131072 + L * 8;
    const short* Qp = (const short*)Qs + (size_t)bh * 131072
                      + (size_t)qt * 1024 + L * 8;
    const bf16x8 qf0 = *(const bf16x8*)(Qp);
    const bf16x8 qf1 = *(const bf16x8*)(Qp + 512);

    f32x4 acc[4] = {};
    float l_i = 0.f;
    const int nkt = qb + 1;

    auto body = [&](const bf16x8* kc0, const bf16x8* kc1, const short* vp0, int kt) {
        const bool diag = (kt == qb);
        const int mlim = diag ? w : 3;
        const bool hi = (mlim >= 2);

        bf16x8 vb0[4], vb1[4];
#pragma unroll
        for (int dt = 0; dt < 4; ++dt) {
            vb0[dt] = *(const bf16x8*)(vp0 + dt * 512);
            if (hi) vb1[dt] = *(const bf16x8*)(vp0 + (4 + dt) * 512);
        }

        f32x4 s[4];
#pragma unroll
        for (int mt = 0; mt < 4; ++mt) {
            if (mt <= mlim) {
                f32x4 z = {};
                z = __builtin_amdgcn_mfma_f32_16x16x32_bf16(kc0[mt], qf0, z, 0, 0, 0);
                s[mt] = __builtin_amdgcn_mfma_f32_16x16x32_bf16(kc1[mt], qf1, z, 0, 0, 0);
                if (diag && mt == mlim) {
#pragma unroll
                    for (int r = 0; r < 4; ++r)
                        if ((g * 4 + r) > lo) s[mt][r] = -1e30f;
                }
            }
        }

#pragma unroll
        for (int mt = 0; mt < 4; ++mt) {
            uint2 u;
            if (mt <= mlim) {
                const float p0 = exp2f(s[mt][0]);
                const float p1 = exp2f(s[mt][1]);
                const float p2 = exp2f(s[mt][2]);
                const float p3 = exp2f(s[mt][3]);
                l_i += (p0 + p1) + (p2 + p3);
                u.x = bfpack_f(p0, p1); u.y = bfpack_f(p2, p3);
            } else {
                u.x = 0u; u.y = 0u;
            }
            *(uint2*)&sP[w][lo * 72 + mt * 16 + g * 4] = u;
        }

        const bf16x8 pb0 = *(const bf16x8*)&sP[w][lo * 72 + g * 8];
        if (hi) {
            const bf16x8 pb1 = *(const bf16x8*)&sP[w][lo * 72 + 32 + g * 8];
#pragma unroll
            for (int dt = 0; dt < 4; ++dt) {
                acc[dt] = __builtin_amdgcn_mfma_f32_16x16x32_bf16(vb0[dt], pb0, acc[dt], 0, 0, 0);
                acc[dt] = __builtin_amdgcn_mfma_f32_16x16x32_bf16(vb1[dt], pb1, acc[dt], 0, 0, 0);
            }
        } else {
#pragma unroll
            for (int dt = 0; dt < 4; ++dt)
                acc[dt] = __builtin_amdgcn_mfma_f32_16x16x32_bf16(vb0[dt], pb0, acc[dt], 0, 0, 0);
        }
    };

    // software pipeline: A/B K-frag register buffers, incremented pointers
    bf16x8 kA0[4], kA1[4], kB0[4], kB1[4];
    const short* vp = (const short*)Vs + (size_t)bh * 131072 + L * 8;
    const short* kld = Kp;
#pragma unroll
    for (int mt = 0; mt < 4; ++mt) {
        kA0[mt] = *(const bf16x8*)(kld + mt * 1024);
        kA1[mt] = *(const bf16x8*)(kld + mt * 1024 + 512);
    }
    kld += 4096;
    int kt = 0;
#pragma unroll 1
    while (true) {
        if (kt + 1 < nkt) {
#pragma unroll
            for (int mt = 0; mt < 4; ++mt) {
                kB0[mt] = *(const bf16x8*)(kld + mt * 1024);
                kB1[mt] = *(const bf16x8*)(kld + mt * 1024 + 512);
            }
            kld += 4096;
        }
        body(kA0, kA1, vp, kt);
        vp += 4096;
        ++kt;
        if (kt >= nkt) break;
        if (kt + 1 < nkt) {
#pragma unroll
            for (int mt = 0; mt < 4; ++mt) {
                kA0[mt] = *(const bf16x8*)(kld + mt * 1024);
                kA1[mt] = *(const bf16x8*)(kld + mt * 1024 + 512);
            }
            kld += 4096;
        }
        body(kB0, kB1, vp, kt);
        vp += 4096;
        ++kt;
        if (kt >= nkt) break;
    }

    l_i += __shfl_xor(l_i, 16);
    l_i += __shfl_xor(l_i, 32);
    const float f = head_scale[h] / l_i;
    const int q = qt * 16 + lo;
    short* op = (short*)Ob + ((size_t)bi * NSEQ + q) * DMODEL + h * DH + g * 4;
#pragma unroll
    for (int dt = 0; dt < 4; ++dt) {
        uint2 u;
        u.x = bfpack(acc[dt][0] * f, acc[dt][1] * f);
        u.y = bfpack(acc[dt][2] * f, acc[dt][3] * f);
        *(uint2*)(op + dt * 16) = u;
    }
}

// ---------------------------------------------------------------------------
// Kernel 3: out projection, bf16 MFMA (XCD remap), bf16 C2 output.
// ---------------------------------------------------------------------------
__global__ __launch_bounds__(256) void k3_proj(
    const __hip_bfloat16* __restrict__ Ob, const __hip_bfloat16* __restrict__ Wob,
    const float* __restrict__ bo, __hip_bfloat16* __restrict__ C2)
{
    __shared__ short As[128 * 72];
    __shared__ short Bs[128 * 72];
    const int t = threadIdx.x;
    const int w = t >> 6, L = t & 63, lo = L & 15, g = L >> 4;
    const int mh = (w >> 1) << 6, nh = (w & 1) << 6;

    const int lid = (int)(blockIdx.y * gridDim.x + blockIdx.x);
    const int xcd = lid & 7, slot = lid >> 3;
    const int row_blk = xcd * 8 + (slot & 7);
    const int col_blk = slot >> 3;
    const int row0 = row_blk * 128, col0 = col_blk * 128;

    f32x4 acc[4][4] = {};
    for (int k0 = 0; k0 < DMODEL; k0 += 64) {
        __syncthreads();
#pragma unroll
        for (int c = 0; c < 4; ++c) {
            const int idx = c * 256 + t;
            const int m = idx >> 3, kb = idx & 7;
            *(uint4*)&As[m * 72 + kb * 8] =
                *(const uint4*)((const short*)Ob + (size_t)(row0 + m) * 512 + k0 + kb * 8);
            *(uint4*)&Bs[m * 72 + kb * 8] =
                *(const uint4*)((const short*)Wob + (size_t)(col0 + m) * 512 + k0 + kb * 8);
        }
        __syncthreads();
#pragma unroll
        for (int ks = 0; ks < 2; ++ks) {
            bf16x8 af[4], bfr[4];
#pragma unroll
            for (int mi = 0; mi < 4; ++mi)
                af[mi] = *(const bf16x8*)&As[(mh + mi * 16 + lo) * 72 + ks * 32 + g * 8];
#pragma unroll
            for (int ni = 0; ni < 4; ++ni)
                bfr[ni] = *(const bf16x8*)&Bs[(nh + ni * 16 + lo) * 72 + ks * 32 + g * 8];
#pragma unroll
            for (int mi = 0; mi < 4; ++mi)
#pragma unroll
                for (int ni = 0; ni < 4; ++ni)
                    acc[mi][ni] = __builtin_amdgcn_mfma_f32_16x16x32_bf16(
                        af[mi], bfr[ni], acc[mi][ni], 0, 0, 0);
        }
    }
#pragma unroll
    for (int ni = 0; ni < 4; ++ni) {
        const int c = col0 + nh + ni * 16 + lo;
        const float b = bo[c];
#pragma unroll
        for (int mi = 0; mi < 4; ++mi) {
#pragma unroll
            for (int r = 0; r < 4; ++r) {
                const int m = row0 + mh + mi * 16 + g * 4 + r;
                *((short*)C2 + (size_t)m * DMODEL + c) = f2bf_r(acc[mi][ni][r] + b);
            }
        }
    }
}

// ---------------------------------------------------------------------------
// Kernel 4: LayerNorm (bf16 in, fp32 math) + ls_scale + transpose to (n,b,d)
// ---------------------------------------------------------------------------
__global__ __launch_bounds__(256) void k4_ln(
    const __hip_bfloat16* __restrict__ C2, const float* __restrict__ g,
    const float* __restrict__ bln, const float* __restrict__ ls,
    float* __restrict__ out)
{
    const int m = blockIdx.x;
    const int bi = m >> 11, ni = m & (NSEQ - 1);
    const unsigned short* row = (const unsigned short*)C2 + (size_t)m * DMODEL;
    const int t = threadIdx.x;
    float v0 = bf2f(row[t]), v1 = bf2f(row[t + 256]);
    float s = v0 + v1, sq2 = v0 * v0 + v1 * v1;
#pragma unroll
    for (int off = 32; off > 0; off >>= 1) {
        s += __shfl_down(s, off);
        sq2 += __shfl_down(sq2, off);
    }
    __shared__ float red[8];
    const int wid = t >> 6;
    if ((t & 63) == 0) { red[wid] = s; red[wid + 4] = sq2; }
    __syncthreads();
    s = red[0] + red[1] + red[2] + red[3];
    sq2 = red[4] + red[5] + red[6] + red[7];
    const float mean = s * (1.f / 512.f);
    const float var = sq2 * (1.f / 512.f) - mean * mean;
    const float rstd = rsqrtf(var + 1e-5f);
    float* ob = out + ((size_t)ni * NB + bi) * DMODEL;
    ob[t]       = ((v0 - mean) * rstd * g[t]       + bln[t])       * ls[t];
    ob[t + 256] = ((v1 - mean) * rstd * g[t + 256] + bln[t + 256]) * ls[t + 256];
}

// ---------------------------------------------------------------------------
extern "C" void kernel_launch(void* const* d_in, const int* in_sizes, int n_in,
                              void* d_out, int out_size, void* d_ws, size_t ws_size,
                              hipStream_t stream) {
    const float* x          = (const float*)d_in[0];
    const float* rope       = (const float*)d_in[1];
    const float* Wq         = (const float*)d_in[2];
    const float* Wk         = (const float*)d_in[3];
    const float* Wv         = (const float*)d_in[4];
    const float* Wo         = (const float*)d_in[5];
    const float* bo         = (const float*)d_in[6];
    const float* ln_g       = (const float*)d_in[7];
    const float* ln_b       = (const float*)d_in[8];
    const float* head_scale = (const float*)d_in[9];
    const float* ls_scale   = (const float*)d_in[10];
    float* out = (float*)d_out;

    char* wsb = (char*)d_ws;
    __hip_bfloat16* xb  = (__hip_bfloat16*)(wsb);                       // 8 MB
    __hip_bfloat16* Wb  = (__hip_bfloat16*)(wsb + ((size_t) 8 << 20));  // 2 MB
    __hip_bfloat16* Qs  = (__hip_bfloat16*)(wsb + ((size_t)10 << 20));  // 8 MB
    __hip_bfloat16* Ks  = (__hip_bfloat16*)(wsb + ((size_t)18 << 20));  // 8 MB
    __hip_bfloat16* Vs  = (__hip_bfloat16*)(wsb + ((size_t)26 << 20));  // 8 MB
    __hip_bfloat16* Ob  = (__hip_bfloat16*)(wsb + ((size_t)34 << 20));  // 8 MB
    float*          cs  = (float*)(wsb + ((size_t)42 << 20));           // 2 MB
    float*          sn  = (float*)(wsb + ((size_t)44 << 20));           // 2 MB
    __hip_bfloat16* C2  = (__hip_bfloat16*)(wsb + ((size_t)10 << 20));  // 8.4 MB, overlaps Q/K
    __hip_bfloat16* Wob = Wb + (size_t)1536 * 512;

    k0_convert<<<5632, 256, 0, stream>>>(x, Wq, Wk, Wv, Wo, rope, xb, Wb, cs, sn);
    k1_qkv<<<dim3(64, 12), 256, 0, stream>>>(xb, cs, sn, Wb, Qs, Ks, Vs);
    k2_attn<<<1024, 256, 0, stream>>>(Qs, Ks, Vs, head_scale, Ob);
    k3_proj<<<dim3(64, 4), 256, 0, stream>>>(Ob, Wob, bo, C2);
    k4_ln<<<MROWS, 256, 0, stream>>>(C2, ln_g, ln_b, ls_scale, out);
}

// Round 11
// 177.004 us; speedup vs baseline: 1.0970x; 1.0443x over previous
//
#include <hip/hip_runtime.h>
#include <hip/hip_bf16.h>
#include <math.h>

#define NSEQ 2048
#define NB 4
#define NH 8
#define DH 64
#define DMODEL 512
#define MROWS (NSEQ * 4)

typedef short bf16x8 __attribute__((ext_vector_type(8)));
typedef float f32x4 __attribute__((ext_vector_type(4)));

static __device__ __forceinline__ short f2bf_r(float f) {
    unsigned u = __float_as_uint(f);
    u += 0x7FFF + ((u >> 16) & 1);
    return (short)(u >> 16);
}
static __device__ __forceinline__ unsigned bfpack(float a, float b) {   // RNE
    unsigned ua = __float_as_uint(a); ua += 0x7FFF + ((ua >> 16) & 1);
    unsigned ub = __float_as_uint(b); ub += 0x7FFF + ((ub >> 16) & 1);
    return (ua >> 16) | (ub & 0xFFFF0000u);
}
static __device__ __forceinline__ unsigned bfpack_f(float a, float b) { // fast, p>=0
    unsigned ua = (__float_as_uint(a) + 0x8000u) >> 16;
    unsigned ub = (__float_as_uint(b) + 0x8000u) & 0xFFFF0000u;
    return ua | ub;
}
static __device__ __forceinline__ float bf2f(unsigned short u) {
    return __uint_as_float(((unsigned)u) << 16);
}

// ---------------------------------------------------------------------------
// Kernel 0: one-shot prep: xb bf16 (b,n,d); Wb bf16 cat(Wq,Wk,Wv,Wo);
// cs/sn fp32 cos/sin planes of rope.
// ---------------------------------------------------------------------------
__global__ __launch_bounds__(256) void k0_convert(
    const float* __restrict__ x, const float* __restrict__ Wq,
    const float* __restrict__ Wk, const float* __restrict__ Wv,
    const float* __restrict__ Wo, const float* __restrict__ rope,
    __hip_bfloat16* __restrict__ xb, __hip_bfloat16* __restrict__ Wb,
    float* __restrict__ cs, float* __restrict__ sn)
{
    const int idx = blockIdx.x * 256 + threadIdx.x;
    if (idx < 8192 * 128) {
        const int row = idx >> 7, c = (idx & 127) << 2;
        const int bi = row >> 11, ni = row & 2047;
        float4 v = *(const float4*)(x + ((size_t)(ni * NB + bi)) * DMODEL + c);
        uint2 u; u.x = bfpack(v.x, v.y); u.y = bfpack(v.z, v.w);
        *(uint2*)((short*)xb + (size_t)row * 512 + c) = u;
    } else if (idx < 8192 * 128 + 2048 * 128) {
        const int j = idx - 8192 * 128;
        const int row = j >> 7, c = (j & 127) << 2;
        const float* src = (row < 512) ? Wq : (row < 1024) ? Wk
                         : (row < 1536) ? Wv : Wo;
        const int rr = row & 511;
        float4 v = *(const float4*)(src + (size_t)rr * 512 + c);
        uint2 u; u.x = bfpack(v.x, v.y); u.y = bfpack(v.z, v.w);
        *(uint2*)((short*)Wb + (size_t)row * 512 + c) = u;
    } else {
        const int j = idx - (8192 * 128 + 2048 * 128);   // 0..131071
        float4 f = *(const float4*)(rope + (size_t)j * 4);
        float4 c4, s4;
        __sincosf(f.x, &s4.x, &c4.x);
        __sincosf(f.y, &s4.y, &c4.y);
        __sincosf(f.z, &s4.z, &c4.z);
        __sincosf(f.w, &s4.w, &c4.w);
        *(float4*)(cs + (size_t)j * 4) = c4;
        *(float4*)(sn + (size_t)j * 4) = s4;
    }
}

// ---------------------------------------------------------------------------
// Kernel 1: merged QKV projection (one kernel, region-branched orientation).
// Q/K blocks (col_blk<8): swapped operands C^T = W.x^T -> thread owns 4
// consecutive e; in-thread RoPE; dense uint2 stores to swizzled layout.
// V blocks (col_blk>=8): normal orientation; dense uint2 stores to V^T
// swizzled layout.
//   Q,K: [bh][n>>4][e>>5][((e>>3)&3)*16+(n&15)][e&7]
//   V^T: [bh][n>>5][e>>4][((n>>3)&3)*16+(e&15)][n&7]
// ---------------------------------------------------------------------------
__global__ __launch_bounds__(256) void k1_qkv(
    const __hip_bfloat16* __restrict__ xb, const float* __restrict__ cs,
    const float* __restrict__ sn, const __hip_bfloat16* __restrict__ Wb,
    __hip_bfloat16* __restrict__ Qs, __hip_bfloat16* __restrict__ Ks,
    __hip_bfloat16* __restrict__ Vs)
{
    __shared__ short As[128 * 72];   // x rows (n-dim)
    __shared__ short Bs[128 * 72];   // W rows (e-dim)
    const int t = threadIdx.x;
    const int w = t >> 6, L = t & 63, lo = L & 15, g = L >> 4;
    const int ah = (w >> 1) << 6;    // A-matrix half (rows of A)
    const int bhh = (w & 1) << 6;    // B-matrix half

    const int lid = (int)(blockIdx.y * gridDim.x + blockIdx.x);
    const int xcd = lid & 7, slot = lid >> 3;
    const int row_blk = xcd * 8 + (slot & 7);     // 0..63  (x rows)
    const int col_blk = slot >> 3;                // 0..11  (Wb rows /128)
    const int row0 = row_blk * 128, wrow0 = col_blk * 128;
    const int bi = row0 >> 11, ni0 = row0 & 2047;
    const bool isV = (col_blk >= 8);

    f32x4 acc[4][4] = {};
    for (int k0 = 0; k0 < DMODEL; k0 += 64) {
        __syncthreads();
#pragma unroll
        for (int c = 0; c < 4; ++c) {
            const int idx = c * 256 + t;
            const int m = idx >> 3, kb = idx & 7;
            *(uint4*)&As[m * 72 + kb * 8] =
                *(const uint4*)((const short*)xb + (size_t)(row0 + m) * 512 + k0 + kb * 8);
            *(uint4*)&Bs[m * 72 + kb * 8] =
                *(const uint4*)((const short*)Wb + (size_t)(wrow0 + m) * 512 + k0 + kb * 8);
        }
        __syncthreads();
        const short* Abuf = isV ? As : Bs;
        const short* Bbuf = isV ? Bs : As;
#pragma unroll
        for (int ks = 0; ks < 2; ++ks) {
            bf16x8 af[4], bfr[4];
#pragma unroll
            for (int mi = 0; mi < 4; ++mi)
                af[mi] = *(const bf16x8*)&Abuf[(ah + mi * 16 + lo) * 72 + ks * 32 + g * 8];
#pragma unroll
            for (int ni = 0; ni < 4; ++ni)
                bfr[ni] = *(const bf16x8*)&Bbuf[(bhh + ni * 16 + lo) * 72 + ks * 32 + g * 8];
#pragma unroll
            for (int mi = 0; mi < 4; ++mi)
#pragma unroll
                for (int ni = 0; ni < 4; ++ni)
                    acc[mi][ni] = __builtin_amdgcn_mfma_f32_16x16x32_bf16(
                        af[mi], bfr[ni], acc[mi][ni], 0, 0, 0);
        }
    }

    if (!isV) {
        const float SC = 0.125f * 1.44269504088896f;
        short* outp = (short*)((wrow0 < 512) ? Qs : Ks);
        const float qs = (wrow0 < 512) ? SC : 1.0f;
        const int cbase = wrow0 & 511;
#pragma unroll
        for (int mi = 0; mi < 4; ++mi) {
            const int c0 = cbase + ah + mi * 16 + (g << 2);
            const int h = c0 >> 6, e0 = c0 & 63;
            short* hb = outp + ((size_t)(bi * NH + h)) * 131072
                        + (e0 >> 5) * 512 + ((e0 >> 3) & 3) * 128 + (e0 & 7);
#pragma unroll
            for (int ni = 0; ni < 4; ++ni) {
                const int nseq = ni0 + bhh + ni * 16 + lo;
                const float4 c4 = *(const float4*)(cs + ((size_t)bi * NSEQ + nseq) * DH + e0);
                const float4 s4 = *(const float4*)(sn + ((size_t)bi * NSEQ + nseq) * DH + e0);
                const f32x4 v = acc[mi][ni];
                const float o0 = (v[0] * c4.x - v[1] * s4.x) * qs;
                const float o1 = (v[1] * c4.y + v[0] * s4.y) * qs;
                const float o2 = (v[2] * c4.z - v[3] * s4.z) * qs;
                const float o3 = (v[3] * c4.w + v[2] * s4.w) * qs;
                uint2 u; u.x = bfpack(o0, o1); u.y = bfpack(o2, o3);
                *(uint2*)(hb + (size_t)(nseq >> 4) * 1024 + (nseq & 15) * 8) = u;
            }
        }
    } else {
        const int col0 = wrow0 - 1024;
#pragma unroll
        for (int ni = 0; ni < 4; ++ni) {
            const int c = col0 + bhh + ni * 16 + lo;
            const int h = c >> 6, e = c & 63;
            short* hb = (short*)Vs + ((size_t)(bi * NH + h)) * 131072
                        + (e >> 4) * 512 + (e & 15) * 8;
#pragma unroll
            for (int mi = 0; mi < 4; ++mi) {
                const int nb = ni0 + ah + mi * 16 + g * 4;
                uint2 u;
                u.x = bfpack(acc[mi][ni][0], acc[mi][ni][1]);
                u.y = bfpack(acc[mi][ni][2], acc[mi][ni][3]);
                *(uint2*)(hb + (size_t)(nb >> 5) * 2048 + ((nb >> 3) & 3) * 128
                          + (nb & 7)) = u;
            }
        }
    }
}

// ---------------------------------------------------------------------------
// Kernel 2: causal flash attention — barrier-free, register-pipelined.
// R11: (1) V loads issue BEFORE the K-next prefetch so the PV V-wait is
// vmcnt(8) (K-next stays in flight) instead of vmcnt(0); (2) chunked
// softmax->PV: stage A (keys 0..31) PV MFMAs retire while stage B's exp2
// issues on the VALU/trans pipe — overlaps transcendental + lgkm drains.
// ---------------------------------------------------------------------------
__global__ __launch_bounds__(256, 3) void k2_attn(
    const __hip_bfloat16* __restrict__ Qs, const __hip_bfloat16* __restrict__ Ks,
    const __hip_bfloat16* __restrict__ Vs, const float* __restrict__ head_scale,
    __hip_bfloat16* __restrict__ Ob)
{
    __shared__ short sP[4][16 * 72];   // per-wave P buffer [q][key]

    const int t = threadIdx.x;
    const int w = t >> 6, L = t & 63, lo = L & 15, g = L >> 4;

    const int lid = (int)blockIdx.x;
    const int xcd = lid & 7, slot = lid >> 3;        // 0..127 per XCD
    const int bh = xcd * 4 + (slot & 3);             // 4 heads per XCD
    const int qb = 31 - (slot >> 2);                 // heavy blocks first
    const int qt = qb * 4 + w;
    const int bi = bh >> 3, h = bh & 7;

    const short* Kp = (const short*)Ks + (size_t)bh * 131072 + L * 8;
    const short* Qp = (const short*)Qs + (size_t)bh * 131072
                      + (size_t)qt * 1024 + L * 8;
    const bf16x8 qf0 = *(const bf16x8*)(Qp);
    const bf16x8 qf1 = *(const bf16x8*)(Qp + 512);

    f32x4 acc[4] = {};
    float l_i = 0.f;
    const int nkt = qb + 1;

    // one-tile compute body; kc = current K frags, vb = current V frags
    auto body = [&](const bf16x8* kc0, const bf16x8* kc1,
                    const bf16x8* vb0, const bf16x8* vb1, int kt) {
        const bool diag = (kt == qb);
        const int mlim = diag ? w : 3;
        const bool hi = (mlim >= 2);

        // S^T = K . Q^T
        f32x4 s[4];
#pragma unroll
        for (int mt = 0; mt < 4; ++mt) {
            if (mt <= mlim) {
                f32x4 z = {};
                z = __builtin_amdgcn_mfma_f32_16x16x32_bf16(kc0[mt], qf0, z, 0, 0, 0);
                s[mt] = __builtin_amdgcn_mfma_f32_16x16x32_bf16(kc1[mt], qf1, z, 0, 0, 0);
                if (diag && mt == mlim) {
#pragma unroll
                    for (int r = 0; r < 4; ++r)
                        if ((g * 4 + r) > lo) s[mt][r] = -1e30f;
                }
            }
        }

        // --- stage A: keys 0..31 ---
#pragma unroll
        for (int mt = 0; mt < 2; ++mt) {
            uint2 u;
            if (mt <= mlim) {
                const float p0 = exp2f(s[mt][0]);
                const float p1 = exp2f(s[mt][1]);
                const float p2 = exp2f(s[mt][2]);
                const float p3 = exp2f(s[mt][3]);
                l_i += (p0 + p1) + (p2 + p3);
                u.x = bfpack_f(p0, p1); u.y = bfpack_f(p2, p3);
            } else {
                u.x = 0u; u.y = 0u;
            }
            *(uint2*)&sP[w][lo * 72 + mt * 16 + g * 4] = u;
        }
        const bf16x8 pb0 = *(const bf16x8*)&sP[w][lo * 72 + g * 8];
#pragma unroll
        for (int dt = 0; dt < 4; ++dt)
            acc[dt] = __builtin_amdgcn_mfma_f32_16x16x32_bf16(vb0[dt], pb0, acc[dt], 0, 0, 0);

        // --- stage B: keys 32..63 (exp2 overlaps stage A's MFMAs) ---
        if (hi) {
#pragma unroll
            for (int mt = 2; mt < 4; ++mt) {
                uint2 u;
                if (mt <= mlim) {
                    const float p0 = exp2f(s[mt][0]);
                    const float p1 = exp2f(s[mt][1]);
                    const float p2 = exp2f(s[mt][2]);
                    const float p3 = exp2f(s[mt][3]);
                    l_i += (p0 + p1) + (p2 + p3);
                    u.x = bfpack_f(p0, p1); u.y = bfpack_f(p2, p3);
                } else {
                    u.x = 0u; u.y = 0u;
                }
                *(uint2*)&sP[w][lo * 72 + mt * 16 + g * 4] = u;
            }
            const bf16x8 pb1 = *(const bf16x8*)&sP[w][lo * 72 + 32 + g * 8];
#pragma unroll
            for (int dt = 0; dt < 4; ++dt)
                acc[dt] = __builtin_amdgcn_mfma_f32_16x16x32_bf16(vb1[dt], pb1, acc[dt], 0, 0, 0);
        }
    };

    // software pipeline: A/B K-frag register buffers; V loads issue FIRST
    bf16x8 kA0[4], kA1[4], kB0[4], kB1[4], vA0[4], vA1[4];
    const short* vp = (const short*)Vs + (size_t)bh * 131072 + L * 8;
    const short* kld = Kp;
#pragma unroll
    for (int mt = 0; mt < 4; ++mt) {
        kA0[mt] = *(const bf16x8*)(kld + mt * 1024);
        kA1[mt] = *(const bf16x8*)(kld + mt * 1024 + 512);
    }
    kld += 4096;
    int kt = 0;
#pragma unroll 1
    while (true) {
        {   // V for THIS tile first (PV waits with K-next still in flight)
            const bool hi = !((kt == qb) && w < 2);
#pragma unroll
            for (int dt = 0; dt < 4; ++dt) {
                vA0[dt] = *(const bf16x8*)(vp + dt * 512);
                if (hi) vA1[dt] = *(const bf16x8*)(vp + (4 + dt) * 512);
            }
        }
        if (kt + 1 < nkt) {   // K-next prefetch
#pragma unroll
            for (int mt = 0; mt < 4; ++mt) {
                kB0[mt] = *(const bf16x8*)(kld + mt * 1024);
                kB1[mt] = *(const bf16x8*)(kld + mt * 1024 + 512);
            }
            kld += 4096;
        }
        body(kA0, kA1, vA0, vA1, kt);
        vp += 4096;
        ++kt;
        if (kt >= nkt) break;

        {   // second unrolled half
            const bool hi = !((kt == qb) && w < 2);
#pragma unroll
            for (int dt = 0; dt < 4; ++dt) {
                vA0[dt] = *(const bf16x8*)(vp + dt * 512);
                if (hi) vA1[dt] = *(const bf16x8*)(vp + (4 + dt) * 512);
            }
        }
        if (kt + 1 < nkt) {
#pragma unroll
            for (int mt = 0; mt < 4; ++mt) {
                kA0[mt] = *(const bf16x8*)(kld + mt * 1024);
                kA1[mt] = *(const bf16x8*)(kld + mt * 1024 + 512);
            }
            kld += 4096;
        }
        body(kB0, kB1, vA0, vA1, kt);
        vp += 4096;
        ++kt;
        if (kt >= nkt) break;
    }

    l_i += __shfl_xor(l_i, 16);
    l_i += __shfl_xor(l_i, 32);
    const float f = head_scale[h] / l_i;
    const int q = qt * 16 + lo;
    short* op = (short*)Ob + ((size_t)bi * NSEQ + q) * DMODEL + h * DH + g * 4;
#pragma unroll
    for (int dt = 0; dt < 4; ++dt) {
        uint2 u;
        u.x = bfpack(acc[dt][0] * f, acc[dt][1] * f);
        u.y = bfpack(acc[dt][2] * f, acc[dt][3] * f);
        *(uint2*)(op + dt * 16) = u;
    }
}

// ---------------------------------------------------------------------------
// Kernel 3: out projection, bf16 MFMA (XCD remap), bf16 C2 output.
// ---------------------------------------------------------------------------
__global__ __launch_bounds__(256) void k3_proj(
    const __hip_bfloat16* __restrict__ Ob, const __hip_bfloat16* __restrict__ Wob,
    const float* __restrict__ bo, __hip_bfloat16* __restrict__ C2)
{
    __shared__ short As[128 * 72];
    __shared__ short Bs[128 * 72];
    const int t = threadIdx.x;
    const int w = t >> 6, L = t & 63, lo = L & 15, g = L >> 4;
    const int mh = (w >> 1) << 6, nh = (w & 1) << 6;

    const int lid = (int)(blockIdx.y * gridDim.x + blockIdx.x);
    const int xcd = lid & 7, slot = lid >> 3;
    const int row_blk = xcd * 8 + (slot & 7);
    const int col_blk = slot >> 3;
    const int row0 = row_blk * 128, col0 = col_blk * 128;

    f32x4 acc[4][4] = {};
    for (int k0 = 0; k0 < DMODEL; k0 += 64) {
        __syncthreads();
#pragma unroll
        for (int c = 0; c < 4; ++c) {
            const int idx = c * 256 + t;
            const int m = idx >> 3, kb = idx & 7;
            *(uint4*)&As[m * 72 + kb * 8] =
                *(const uint4*)((const short*)Ob + (size_t)(row0 + m) * 512 + k0 + kb * 8);
            *(uint4*)&Bs[m * 72 + kb * 8] =
                *(const uint4*)((const short*)Wob + (size_t)(col0 + m) * 512 + k0 + kb * 8);
        }
        __syncthreads();
#pragma unroll
        for (int ks = 0; ks < 2; ++ks) {
            bf16x8 af[4], bfr[4];
#pragma unroll
            for (int mi = 0; mi < 4; ++mi)
                af[mi] = *(const bf16x8*)&As[(mh + mi * 16 + lo) * 72 + ks * 32 + g * 8];
#pragma unroll
            for (int ni = 0; ni < 4; ++ni)
                bfr[ni] = *(const bf16x8*)&Bs[(nh + ni * 16 + lo) * 72 + ks * 32 + g * 8];
#pragma unroll
            for (int mi = 0; mi < 4; ++mi)
#pragma unroll
                for (int ni = 0; ni < 4; ++ni)
                    acc[mi][ni] = __builtin_amdgcn_mfma_f32_16x16x32_bf16(
                        af[mi], bfr[ni], acc[mi][ni], 0, 0, 0);
        }
    }
#pragma unroll
    for (int ni = 0; ni < 4; ++ni) {
        const int c = col0 + nh + ni * 16 + lo;
        const float b = bo[c];
#pragma unroll
        for (int mi = 0; mi < 4; ++mi) {
#pragma unroll
            for (int r = 0; r < 4; ++r) {
                const int m = row0 + mh + mi * 16 + g * 4 + r;
                *((short*)C2 + (size_t)m * DMODEL + c) = f2bf_r(acc[mi][ni][r] + b);
            }
        }
    }
}

// ---------------------------------------------------------------------------
// Kernel 4: LayerNorm (bf16 in, fp32 math) + ls_scale + transpose to (n,b,d)
// ---------------------------------------------------------------------------
__global__ __launch_bounds__(256) void k4_ln(
    const __hip_bfloat16* __restrict__ C2, const float* __restrict__ g,
    const float* __restrict__ bln, const float* __restrict__ ls,
    float* __restrict__ out)
{
    const int m = blockIdx.x;
    const int bi = m >> 11, ni = m & (NSEQ - 1);
    const unsigned short* row = (const unsigned short*)C2 + (size_t)m * DMODEL;
    const int t = threadIdx.x;
    float v0 = bf2f(row[t]), v1 = bf2f(row[t + 256]);
    float s = v0 + v1, sq2 = v0 * v0 + v1 * v1;
#pragma unroll
    for (int off = 32; off > 0; off >>= 1) {
        s += __shfl_down(s, off);
        sq2 += __shfl_down(sq2, off);
    }
    __shared__ float red[8];
    const int wid = t >> 6;
    if ((t & 63) == 0) { red[wid] = s; red[wid + 4] = sq2; }
    __syncthreads();
    s = red[0] + red[1] + red[2] + red[3];
    sq2 = red[4] + red[5] + red[6] + red[7];
    const float mean = s * (1.f / 512.f);
    const float var = sq2 * (1.f / 512.f) - mean * mean;
    const float rstd = rsqrtf(var + 1e-5f);
    float* ob = out + ((size_t)ni * NB + bi) * DMODEL;
    ob[t]       = ((v0 - mean) * rstd * g[t]       + bln[t])       * ls[t];
    ob[t + 256] = ((v1 - mean) * rstd * g[t + 256] + bln[t + 256]) * ls[t + 256];
}

// ---------------------------------------------------------------------------
extern "C" void kernel_launch(void* const* d_in, const int* in_sizes, int n_in,
                              void* d_out, int out_size, void* d_ws, size_t ws_size,
                              hipStream_t stream) {
    const float* x          = (const float*)d_in[0];
    const float* rope       = (const float*)d_in[1];
    const float* Wq         = (const float*)d_in[2];
    const float* Wk         = (const float*)d_in[3];
    const float* Wv         = (const float*)d_in[4];
    const float* Wo         = (const float*)d_in[5];
    const float* bo         = (const float*)d_in[6];
    const float* ln_g       = (const float*)d_in[7];
    const float* ln_b       = (const float*)d_in[8];
    const float* head_scale = (const float*)d_in[9];
    const float* ls_scale   = (const float*)d_in[10];
    float* out = (float*)d_out;

    char* wsb = (char*)d_ws;
    __hip_bfloat16* xb  = (__hip_bfloat16*)(wsb);                       // 8 MB
    __hip_bfloat16* Wb  = (__hip_bfloat16*)(wsb + ((size_t) 8 << 20));  // 2 MB
    __hip_bfloat16* Qs  = (__hip_bfloat16*)(wsb + ((size_t)10 << 20));  // 8 MB
    __hip_bfloat16* Ks  = (__hip_bfloat16*)(wsb + ((size_t)18 << 20));  // 8 MB
    __hip_bfloat16* Vs  = (__hip_bfloat16*)(wsb + ((size_t)26 << 20));  // 8 MB
    __hip_bfloat16* Ob  = (__hip_bfloat16*)(wsb + ((size_t)34 << 20));  // 8 MB
    float*          cs  = (float*)(wsb + ((size_t)42 << 20));           // 2 MB
    float*          sn  = (float*)(wsb + ((size_t)44 << 20));           // 2 MB
    __hip_bfloat16* C2  = (__hip_bfloat16*)(wsb + ((size_t)10 << 20));  // 8.4 MB, overlaps Q/K
    __hip_bfloat16* Wob = Wb + (size_t)1536 * 512;

    k0_convert<<<5632, 256, 0, stream>>>(x, Wq, Wk, Wv, Wo, rope, xb, Wb, cs, sn);
    k1_qkv<<<dim3(64, 12), 256, 0, stream>>>(xb, cs, sn, Wb, Qs, Ks, Vs);
    k2_attn<<<1024, 256, 0, stream>>>(Qs, Ks, Vs, head_scale, Ob);
    k3_proj<<<dim3(64, 4), 256, 0, stream>>>(Ob, Wob, bo, C2);
    k4_ln<<<MROWS, 256, 0, stream>>>(C2, ln_g, ln_b, ls_scale, out);
}